// Round 1
// baseline (350.251 us; speedup 1.0000x reference)
//
#include <hip/hip_runtime.h>

#define NN 2048
#define DD 128

typedef _Float16 f16x8 __attribute__((ext_vector_type(8)));
typedef float f32x4 __attribute__((ext_vector_type(4)));

// ---------------------------------------------------------------------------
// prep: Wt[l][d][k] = fp16(W[l][k][d])  (3 layers, 48K elems — trivial)
// ---------------------------------------------------------------------------
__global__ __launch_bounds__(256) void prep_kernel(
    const float* __restrict__ W, _Float16* __restrict__ Wt) {
  int idx = blockIdx.x * 256 + threadIdx.x;
  int l = idx >> 14, r = idx & 16383, d = r >> 7, k = r & 127;
  Wt[idx] = (_Float16)W[l * 16384 + k * 128 + d];
}

// ---------------------------------------------------------------------------
// gemmY (layer 0 only): Yt[b][d][n] = sum_k X[b][n][k] * W0[k][d]
// ---------------------------------------------------------------------------
__global__ __launch_bounds__(256) void gemmY_kernel(
    const float* __restrict__ X, const _Float16* __restrict__ Wt,
    _Float16* __restrict__ Yt) {
  const int bx = blockIdx.x;
  const int batch = bx & 7, n0 = (bx >> 3) * 32;
  const int tid = threadIdx.x, lane = tid & 63, wave = tid >> 6;
  const int quad = lane >> 4, l15 = lane & 15, d0 = wave * 32;
  const float* Xb = X + (size_t)(batch * NN + n0) * DD;
  f32x4 acc[2][2] = {};
#pragma unroll
  for (int kk = 0; kk < 128; kk += 32) {
    f16x8 a0 = *(const f16x8*)(Wt + (d0 + l15) * DD + kk + quad * 8);
    f16x8 a1 = *(const f16x8*)(Wt + (d0 + 16 + l15) * DD + kk + quad * 8);
#pragma unroll
    for (int fi = 0; fi < 2; ++fi) {
      const float* xp = Xb + (size_t)(fi * 16 + l15) * DD + kk + quad * 8;
      float4 x0 = *(const float4*)xp;
      float4 x1 = *(const float4*)(xp + 4);
      f16x8 b = {(_Float16)x0.x, (_Float16)x0.y, (_Float16)x0.z, (_Float16)x0.w,
                 (_Float16)x1.x, (_Float16)x1.y, (_Float16)x1.z, (_Float16)x1.w};
      acc[0][fi] = __builtin_amdgcn_mfma_f32_16x16x32_f16(a0, b, acc[0][fi], 0, 0, 0);
      acc[1][fi] = __builtin_amdgcn_mfma_f32_16x16x32_f16(a1, b, acc[1][fi], 0, 0, 0);
    }
  }
  _Float16* YtB = Yt + (size_t)batch * DD * NN;
#pragma unroll
  for (int df = 0; df < 2; ++df)
#pragma unroll
    for (int fi = 0; fi < 2; ++fi)
#pragma unroll
      for (int r = 0; r < 4; ++r)
        YtB[(size_t)(d0 + df * 16 + quad * 4 + r) * NN + n0 + fi * 16 + l15] =
            (_Float16)acc[df][fi][r];
}

// ---------------------------------------------------------------------------
// agg (legacy, fp32 adj via LDS): layer 1 (and fallback layers).
// SAVE: additionally writes fp16 adj (adjH) + reciprocal row-denominators (rdg)
// so later layers can skip conversion/rowsum/LDS entirely.
// ---------------------------------------------------------------------------
template<bool SAVE, bool LAST>
__global__ __launch_bounds__(256) void agg_kernel(
    const float* __restrict__ adj, const _Float16* __restrict__ Yt,
    const float* __restrict__ bias, const _Float16* __restrict__ Wn,
    _Float16* __restrict__ Ytn, float* __restrict__ out,
    _Float16* __restrict__ adjH, float* __restrict__ rdg) {
  __shared__ _Float16 Bs[2][32 * 64];   // swizzled flat, 2 x 4 KB
  __shared__ float Xs[32][132];         // epilogue activation tile
  __shared__ float bsh[128];
  __shared__ float rd[32];

  const int tid = threadIdx.x, bx = blockIdx.x;
  const int batch = bx & 7, i0 = (bx >> 3) * 32;
  const int lane = tid & 63, wave = tid >> 6;
  const int quad = lane >> 4, l15 = lane & 15, d0 = wave * 32;
  const int ai = tid >> 3, ac = tid & 7;       // adj staging: 8 thr/row
  const int sc = ac ^ (ai & 7);                // swizzled 16-B chunk slot

  const float* adjR = adj + (size_t)(batch * NN + i0 + ai) * NN + ac * 8;
  const _Float16* YtB = Yt + (size_t)batch * DD * NN;
  const _Float16* Ya0 = YtB + (size_t)(d0 + l15) * NN;
  const _Float16* Ya1 = YtB + (size_t)(d0 + 16 + l15) * NN;
  _Float16* AdjHW = SAVE ? adjH + (size_t)(batch * NN + i0 + ai) * NN + ac * 8 : nullptr;

  if (tid < 128) bsh[tid] = bias[tid];

  f32x4 acc[2][2] = {};
  float rowsum = 0.f;

  // prefetch tile 0
  float4 av0 = *(const float4*)(adjR);
  float4 av1 = *(const float4*)(adjR + 4);
  f16x8 a[2][2];
#pragma unroll
  for (int k2 = 0; k2 < 2; ++k2) {
    a[k2][0] = *(const f16x8*)(Ya0 + k2 * 32 + quad * 8);
    a[k2][1] = *(const f16x8*)(Ya1 + k2 * 32 + quad * 8);
  }

  for (int ko = 0; ko < 32; ++ko) {
    rowsum += ((av0.x + av0.y) + (av0.z + av0.w)) + ((av1.x + av1.y) + (av1.z + av1.w));
    f16x8 h = {(_Float16)av0.x, (_Float16)av0.y, (_Float16)av0.z, (_Float16)av0.w,
               (_Float16)av1.x, (_Float16)av1.y, (_Float16)av1.z, (_Float16)av1.w};
    *(f16x8*)(&Bs[ko & 1][ai * 64 + sc * 8]) = h;
    if (SAVE) *(f16x8*)(AdjHW + ko * 64) = h;
    f16x8 an[2][2];
    if (ko < 31) {
      const int kb = (ko + 1) * 64;
      av0 = *(const float4*)(adjR + kb);
      av1 = *(const float4*)(adjR + kb + 4);
#pragma unroll
      for (int k2 = 0; k2 < 2; ++k2) {
        an[k2][0] = *(const f16x8*)(Ya0 + kb + k2 * 32 + quad * 8);
        an[k2][1] = *(const f16x8*)(Ya1 + kb + k2 * 32 + quad * 8);
      }
    }
    __syncthreads();
    const _Float16* B = Bs[ko & 1];
#pragma unroll
    for (int k2 = 0; k2 < 2; ++k2)
#pragma unroll
      for (int fi = 0; fi < 2; ++fi) {
        const int row = fi * 16 + l15;
        const int ch = (k2 * 4 + quad) ^ (row & 7);
        f16x8 b = *(const f16x8*)(&B[row * 64 + ch * 8]);
        acc[0][fi] = __builtin_amdgcn_mfma_f32_16x16x32_f16(a[k2][0], b, acc[0][fi], 0, 0, 0);
        acc[1][fi] = __builtin_amdgcn_mfma_f32_16x16x32_f16(a[k2][1], b, acc[1][fi], 0, 0, 0);
      }
#pragma unroll
    for (int k2 = 0; k2 < 2; ++k2) { a[k2][0] = an[k2][0]; a[k2][1] = an[k2][1]; }
  }

  rowsum += __shfl_xor(rowsum, 1);
  rowsum += __shfl_xor(rowsum, 2);
  rowsum += __shfl_xor(rowsum, 4);
  if (ac == 0) {
    float v = 1.0f / (rowsum + 1.0f);
    rd[ai] = v;
    if (SAVE) rdg[batch * NN + i0 + ai] = v;
  }
  __syncthreads();

#pragma unroll
  for (int df = 0; df < 2; ++df)
#pragma unroll
    for (int fi = 0; fi < 2; ++fi)
#pragma unroll
      for (int r = 0; r < 4; ++r) {
        int d = d0 + df * 16 + quad * 4 + r;
        int i = fi * 16 + l15;
        Xs[i][d] = fmaxf((acc[df][fi][r] + bsh[d]) * rd[i], 0.f);
      }
  __syncthreads();

  if (LAST) {
    float* outB = out + (size_t)(batch * NN + i0) * DD;
#pragma unroll
    for (int u = 0; u < 4; ++u) {
      int c = tid + 256 * u;
      int i = c >> 5, f4 = (c & 31) * 4;
      *(float4*)(outB + (size_t)i * DD + f4) = *(const float4*)&Xs[i][f4];
    }
  } else {
    f32x4 acc2[2][2] = {};
#pragma unroll
    for (int kk = 0; kk < 128; kk += 32) {
      f16x8 a0 = *(const f16x8*)(Wn + (d0 + l15) * DD + kk + quad * 8);
      f16x8 a1 = *(const f16x8*)(Wn + (d0 + 16 + l15) * DD + kk + quad * 8);
#pragma unroll
      for (int fi = 0; fi < 2; ++fi) {
        const float* xp = &Xs[fi * 16 + l15][kk + quad * 8];
        f16x8 b = {(_Float16)xp[0], (_Float16)xp[1], (_Float16)xp[2], (_Float16)xp[3],
                   (_Float16)xp[4], (_Float16)xp[5], (_Float16)xp[6], (_Float16)xp[7]};
        acc2[0][fi] = __builtin_amdgcn_mfma_f32_16x16x32_f16(a0, b, acc2[0][fi], 0, 0, 0);
        acc2[1][fi] = __builtin_amdgcn_mfma_f32_16x16x32_f16(a1, b, acc2[1][fi], 0, 0, 0);
      }
    }
    _Float16* YnB = Ytn + (size_t)batch * DD * NN;
#pragma unroll
    for (int df = 0; df < 2; ++df)
#pragma unroll
      for (int fi = 0; fi < 2; ++fi)
#pragma unroll
        for (int r = 0; r < 4; ++r)
          YnB[(size_t)(d0 + df * 16 + quad * 4 + r) * NN + i0 + fi * 16 + l15] =
              (_Float16)acc2[df][fi][r];
  }
}

// ---------------------------------------------------------------------------
// aggf16: lean agg for layers 2/3. fp16 adj straight from global as MFMA
// B-fragments (L1 broadcast across the 4 waves), precomputed 1/(rowsum+1),
// ZERO barriers in the main loop (waves fully independent), 2-deep register
// double buffer; full unroll folds all k-tile addresses into load immediates.
// ---------------------------------------------------------------------------
__device__ __forceinline__ void loadf16(f16x8 (&AF)[2][2], f16x8 (&BF)[2][2],
    const _Float16* Ya0, const _Float16* Ya1,
    const _Float16* Ba0, const _Float16* Ba1, int kb) {
#pragma unroll
  for (int k2 = 0; k2 < 2; ++k2) {
    AF[k2][0] = *(const f16x8*)(Ya0 + kb + k2 * 32);
    AF[k2][1] = *(const f16x8*)(Ya1 + kb + k2 * 32);
    BF[k2][0] = *(const f16x8*)(Ba0 + kb + k2 * 32);
    BF[k2][1] = *(const f16x8*)(Ba1 + kb + k2 * 32);
  }
}

__device__ __forceinline__ void mfma8(const f16x8 (&AF)[2][2],
    const f16x8 (&BF)[2][2], f32x4 (&acc)[2][2]) {
#pragma unroll
  for (int k2 = 0; k2 < 2; ++k2)
#pragma unroll
    for (int fi = 0; fi < 2; ++fi) {
      acc[0][fi] = __builtin_amdgcn_mfma_f32_16x16x32_f16(AF[k2][0], BF[k2][fi], acc[0][fi], 0, 0, 0);
      acc[1][fi] = __builtin_amdgcn_mfma_f32_16x16x32_f16(AF[k2][1], BF[k2][fi], acc[1][fi], 0, 0, 0);
    }
}

template<bool LAST>
__global__ __launch_bounds__(256) void aggf16_kernel(
    const _Float16* __restrict__ adjH, const float* __restrict__ rdg,
    const _Float16* __restrict__ Yt, const float* __restrict__ bias,
    const _Float16* __restrict__ Wn, _Float16* __restrict__ Ytn,
    float* __restrict__ out) {
  __shared__ float Xs[32][132];

  const int tid = threadIdx.x, bx = blockIdx.x;
  const int batch = bx & 7, i0 = (bx >> 3) * 32;
  const int lane = tid & 63, wave = tid >> 6;
  const int quad = lane >> 4, l15 = lane & 15, d0 = wave * 32;

  const _Float16* YtB = Yt + (size_t)batch * DD * NN;
  const _Float16* Ya0 = YtB + (size_t)(d0 + l15) * NN + quad * 8;
  const _Float16* Ya1 = YtB + (size_t)(d0 + 16 + l15) * NN + quad * 8;
  const _Float16* AdjB = adjH + (size_t)(batch * NN + i0) * NN;
  const _Float16* Ba0 = AdjB + (size_t)l15 * NN + quad * 8;
  const _Float16* Ba1 = AdjB + (size_t)(16 + l15) * NN + quad * 8;

  // per-lane scalars: denominators for the two i-rows, bias for the d-cols
  const float* rdb = rdg + batch * NN + i0;
  float rdv0 = rdb[l15], rdv1 = rdb[16 + l15];
  float4 bv0 = *(const float4*)(bias + d0 + quad * 4);
  float4 bv1 = *(const float4*)(bias + d0 + 16 + quad * 4);

  f32x4 acc[2][2] = {};
  f16x8 aA[2][2], bA[2][2], aB[2][2], bB[2][2];

  loadf16(aA, bA, Ya0, Ya1, Ba0, Ba1, 0);
#pragma unroll
  for (int ko = 0; ko < 32; ko += 2) {
    if (ko + 1 < 32) loadf16(aB, bB, Ya0, Ya1, Ba0, Ba1, (ko + 1) * 64);
    mfma8(aA, bA, acc);
    if (ko + 2 < 32) loadf16(aA, bA, Ya0, Ya1, Ba0, Ba1, (ko + 2) * 64);
    mfma8(aB, bB, acc);
  }

  // activation tile: relu((Z+b)*rd), transposed into Xs[i][d]
#pragma unroll
  for (int df = 0; df < 2; ++df)
#pragma unroll
    for (int fi = 0; fi < 2; ++fi)
#pragma unroll
      for (int r = 0; r < 4; ++r) {
        int d = d0 + df * 16 + quad * 4 + r;
        float bia = df ? ((const float*)&bv1)[r] : ((const float*)&bv0)[r];
        float rv = fi ? rdv1 : rdv0;
        Xs[fi * 16 + l15][d] = fmaxf((acc[df][fi][r] + bia) * rv, 0.f);
      }
  __syncthreads();   // the ONLY barrier

  if (LAST) {
    float* outB = out + (size_t)(batch * NN + i0) * DD;
#pragma unroll
    for (int u = 0; u < 4; ++u) {
      int c = tid + 256 * u;
      int i = c >> 5, f4 = (c & 31) * 4;
      *(float4*)(outB + (size_t)i * DD + f4) = *(const float4*)&Xs[i][f4];
    }
  } else {
    f32x4 acc2[2][2] = {};
#pragma unroll
    for (int kk = 0; kk < 128; kk += 32) {
      f16x8 a0 = *(const f16x8*)(Wn + (d0 + l15) * DD + kk + quad * 8);
      f16x8 a1 = *(const f16x8*)(Wn + (d0 + 16 + l15) * DD + kk + quad * 8);
#pragma unroll
      for (int fi = 0; fi < 2; ++fi) {
        const float* xp = &Xs[fi * 16 + l15][kk + quad * 8];
        f16x8 b = {(_Float16)xp[0], (_Float16)xp[1], (_Float16)xp[2], (_Float16)xp[3],
                   (_Float16)xp[4], (_Float16)xp[5], (_Float16)xp[6], (_Float16)xp[7]};
        acc2[0][fi] = __builtin_amdgcn_mfma_f32_16x16x32_f16(a0, b, acc2[0][fi], 0, 0, 0);
        acc2[1][fi] = __builtin_amdgcn_mfma_f32_16x16x32_f16(a1, b, acc2[1][fi], 0, 0, 0);
      }
    }
    _Float16* YnB = Ytn + (size_t)batch * DD * NN;
#pragma unroll
    for (int df = 0; df < 2; ++df)
#pragma unroll
      for (int fi = 0; fi < 2; ++fi)
#pragma unroll
        for (int r = 0; r < 4; ++r)
          YnB[(size_t)(d0 + df * 16 + quad * 4 + r) * NN + i0 + fi * 16 + l15] =
              (_Float16)acc2[df][fi][r];
  }
}

extern "C" void kernel_launch(void* const* d_in, const int* in_sizes, int n_in,
                              void* d_out, int out_size, void* d_ws, size_t ws_size,
                              hipStream_t stream) {
  const float* x0   = (const float*)d_in[0];   // [8,2048,128]
  const float* adj  = (const float*)d_in[1];   // [8,2048,2048]
  const float* W    = (const float*)d_in[2];   // [3,128,128]
  const float* bias = (const float*)d_in[3];   // [3,128]
  float* out = (float*)d_out;

  _Float16* Wt   = (_Float16*)d_ws;                              // 96 KB fp16 W^T x3
  _Float16* YtA  = (_Float16*)((char*)d_ws + 131072);            // 4 MiB
  float*    rdg  = (float*)((char*)d_ws + 131072 + (4u << 20));  // 64 KB
  _Float16* adjH = (_Float16*)((char*)d_ws + (8u << 20));        // 64 MiB fp16 adj
  _Float16* YtB_ = (_Float16*)d_out;                             // d_out doubles as f16 scratch

  const bool big = ws_size >= ((8ull + 64ull) << 20);

  dim3 blk(256);
  prep_kernel <<<192, blk, 0, stream>>>(W, Wt);
  gemmY_kernel<<<512, blk, 0, stream>>>(x0, Wt, YtA);
  if (big) {
    // layer 1: fp32 adj staged via LDS; emits fp16 adj + reciprocal denominators
    agg_kernel<true, false><<<512, blk, 0, stream>>>(adj, YtA, bias, Wt + 16384, YtB_, nullptr, adjH, rdg);
    // layers 2/3: lean barrier-free fp16-adj kernels
    aggf16_kernel<false><<<512, blk, 0, stream>>>(adjH, rdg, YtB_, bias + 128, Wt + 32768, YtA, nullptr);
    aggf16_kernel<true ><<<512, blk, 0, stream>>>(adjH, rdg, YtA, bias + 256, nullptr, nullptr, out);
  } else {
    // fallback: original 3-pass fp32 path
    agg_kernel<false, false><<<512, blk, 0, stream>>>(adj, YtA,  bias,       Wt + 16384, YtB_, nullptr, nullptr, nullptr);
    agg_kernel<false, false><<<512, blk, 0, stream>>>(adj, YtB_, bias + 128, Wt + 32768, YtA,  nullptr, nullptr, nullptr);
    agg_kernel<false, true ><<<512, blk, 0, stream>>>(adj, YtA,  bias + 256, nullptr,    nullptr, out, nullptr, nullptr);
  }
}

// Round 2
// 294.437 us; speedup vs baseline: 1.1896x; 1.1896x over previous
//
#include <hip/hip_runtime.h>

#define NN 2048
#define DD 128

typedef _Float16 f16x8 __attribute__((ext_vector_type(8)));
typedef float f32x4 __attribute__((ext_vector_type(4)));

// ===========================================================================
// Fragment-tiled fp16 layout for 16x16x32 MFMA operands, matrix [R][C]:
//   tile (rt, ct) = rows rt*16..+16, cols ct*32..+32, stored as 512 fp16
//   at blockbase = (rt*(C/32) + ct)*512 ; element lane*8+e holds
//   M[rt*16 + (lane&15)][ct*32 + (lane>>4)*8 + e].
// Every wave frag load/store = contiguous 1 KB. Used for adjH, Xt, Y1t, Y2t.
// ===========================================================================

// ---------------------------------------------------------------------------
// prep: Wt[l][d][k] = fp16(W[l][k][d])  (3 layers, 48K elems — trivial)
// ---------------------------------------------------------------------------
__global__ __launch_bounds__(256) void prep_kernel(
    const float* __restrict__ W, _Float16* __restrict__ Wt) {
  int idx = blockIdx.x * 256 + threadIdx.x;
  int l = idx >> 14, r = idx & 16383, d = r >> 7, k = r & 127;
  Wt[idx] = (_Float16)W[l * 16384 + k * 128 + d];
}

// ---------------------------------------------------------------------------
// prepAdj: adj fp32 -> fragment-tiled fp16 adjH, plus rdg = 1/(rowsum+1).
// Grid 1024 = (batch, it row-tile of 16). Pure streaming, coalesced both ways.
// ---------------------------------------------------------------------------
__global__ __launch_bounds__(256) void prepAdj_kernel(
    const float* __restrict__ adj, _Float16* __restrict__ adjH,
    float* __restrict__ rdg) {
  __shared__ float rs[16][4];
  const int bx = blockIdx.x, tid = threadIdx.x;
  const int it = bx & 127, batch = bx >> 7;
  const int lane = tid & 63, wave = tid >> 6;
  const int quad = lane >> 4, l15 = lane & 15;

  const float* Ap = adj + ((size_t)(batch * NN) + it * 16 + l15) * NN + quad * 8;
  _Float16* Hp = adjH + (size_t)batch * NN * NN + ((size_t)it * 64) * 512 + lane * 8;

  float s = 0.f;
#pragma unroll
  for (int j = 0; j < 16; ++j) {
    const int ct = wave + 4 * j;
    float4 a0 = *(const float4*)(Ap + ct * 32);
    float4 a1 = *(const float4*)(Ap + ct * 32 + 4);
    s += ((a0.x + a0.y) + (a0.z + a0.w)) + ((a1.x + a1.y) + (a1.z + a1.w));
    f16x8 h = {(_Float16)a0.x, (_Float16)a0.y, (_Float16)a0.z, (_Float16)a0.w,
               (_Float16)a1.x, (_Float16)a1.y, (_Float16)a1.z, (_Float16)a1.w};
    *(f16x8*)(Hp + (size_t)ct * 512) = h;
  }
  // reduce across the 4 quads holding the same row l15
  s += __shfl_xor(s, 16);
  s += __shfl_xor(s, 32);
  if (lane < 16) rs[lane][wave] = s;
  __syncthreads();
  if (tid < 16) {
    float t = rs[tid][0] + rs[tid][1] + rs[tid][2] + rs[tid][3];
    rdg[batch * NN + it * 16 + tid] = 1.0f / (t + 1.0f);
  }
}

// ---------------------------------------------------------------------------
// transposeX: X[b][n][d] fp32 -> fragment-tiled fp16 Xt (rows=d 128, cols=n).
// Grid 512 = (batch, nt col-tile of 32). Tiny (8 MB in / 4 MB out).
// ---------------------------------------------------------------------------
__global__ __launch_bounds__(256) void transposeX_kernel(
    const float* __restrict__ X, _Float16* __restrict__ Xt) {
  const int bx = blockIdx.x, tid = threadIdx.x;
  const int batch = bx & 7, nt = bx >> 3;
  const int lane = tid & 63, wave = tid >> 6;
  const int quad = lane >> 4, l15 = lane & 15;
  const size_t batA = (size_t)batch * (128 * NN);
#pragma unroll
  for (int dtl = 0; dtl < 2; ++dtl) {
    const int dt = wave * 2 + dtl;
    const float* Xp = X + ((size_t)(batch * NN) + nt * 32 + quad * 8) * DD + dt * 16 + l15;
    f16x8 v;
#pragma unroll
    for (int e = 0; e < 8; ++e) v[e] = (_Float16)Xp[(size_t)e * DD];
    *(f16x8*)(Xt + batA + ((size_t)(dt * 64 + nt)) * 512 + lane * 8) = v;
  }
}

// ---------------------------------------------------------------------------
// epilogue helper: acc2[dout][i] += sum_k Wf-frag[dout][k] * fp16(Xs[i][k])
// ---------------------------------------------------------------------------
__device__ __forceinline__ void epiGemm(const float (*Xs)[132],
    const _Float16* __restrict__ Wf, int d0, int quad, int l15,
    f32x4 (&o)[2][2]) {
#pragma unroll
  for (int kk = 0; kk < 128; kk += 32) {
    f16x8 a0 = *(const f16x8*)(Wf + (d0 + l15) * DD + kk + quad * 8);
    f16x8 a1 = *(const f16x8*)(Wf + (d0 + 16 + l15) * DD + kk + quad * 8);
#pragma unroll
    for (int fi = 0; fi < 2; ++fi) {
      const float* xp = &Xs[fi * 16 + l15][kk + quad * 8];
      f16x8 b = {(_Float16)xp[0], (_Float16)xp[1], (_Float16)xp[2], (_Float16)xp[3],
                 (_Float16)xp[4], (_Float16)xp[5], (_Float16)xp[6], (_Float16)xp[7]};
      o[0][fi] = __builtin_amdgcn_mfma_f32_16x16x32_f16(a0, b, o[0][fi], 0, 0, 0);
      o[1][fi] = __builtin_amdgcn_mfma_f32_16x16x32_f16(a1, b, o[1][fi], 0, 0, 0);
    }
  }
}

// ---------------------------------------------------------------------------
// aggT: main GCN layer. acc[d][i] = sum_n At[d][n] * adjH[i][n], both
// operands fragment-tiled -> every load is a coalesced 1 KB wave load,
// ZERO barriers in the 64-iteration main loop, 2-deep register dbuf.
// MODE 0 (first): epi = T@W0 -> +b,*rd,relu -> @W1 -> frag-store Y1t
// MODE 1 (mid):   epi = +b,*rd,relu -> @W2 -> frag-store Y2t
// MODE 2 (last):  epi = +b,*rd,relu -> fp32 out
// ---------------------------------------------------------------------------
template<int MODE>
__global__ __launch_bounds__(256, 4) void aggT_kernel(
    const _Float16* __restrict__ adjH, const float* __restrict__ rdg,
    const _Float16* __restrict__ At, const float* __restrict__ bias,
    const _Float16* __restrict__ WA, const _Float16* __restrict__ WB,
    _Float16* __restrict__ Yout, float* __restrict__ out) {
  __shared__ float Xs[32][132];
  __shared__ float bsh[128];
  __shared__ float rdsh[32];

  const int tid = threadIdx.x, bx = blockIdx.x;
  const int batch = bx & 7, i0 = (bx >> 3) * 32;
  const int lane = tid & 63, wave = tid >> 6;
  const int quad = lane >> 4, l15 = lane & 15, d0 = wave * 32;

  const size_t batA = (size_t)batch * (128 * NN);
  const size_t batB = (size_t)batch * ((size_t)NN * NN);
  const int it0 = i0 >> 4;
  const _Float16* Ap0 = At + batA + ((size_t)(2 * wave) * 64) * 512 + lane * 8;
  const _Float16* Ap1 = At + batA + ((size_t)(2 * wave + 1) * 64) * 512 + lane * 8;
  const _Float16* Bp0 = adjH + batB + ((size_t)it0 * 64) * 512 + lane * 8;
  const _Float16* Bp1 = adjH + batB + ((size_t)(it0 + 1) * 64) * 512 + lane * 8;

  if (tid < 128) bsh[tid] = bias[tid];
  if (tid < 32) rdsh[tid] = rdg[batch * NN + i0 + tid];
  __syncthreads();

  f32x4 acc[2][2] = {};
  f16x8 qa0[2], qa1[2], qb0[2], qb1[2];
#define LDT(ct, s)                                  \
  { qa0[s] = *(const f16x8*)(Ap0 + (ct) * 512);     \
    qa1[s] = *(const f16x8*)(Ap1 + (ct) * 512);     \
    qb0[s] = *(const f16x8*)(Bp0 + (ct) * 512);     \
    qb1[s] = *(const f16x8*)(Bp1 + (ct) * 512); }
#define MMT(s)                                                                          \
  { acc[0][0] = __builtin_amdgcn_mfma_f32_16x16x32_f16(qa0[s], qb0[s], acc[0][0], 0, 0, 0); \
    acc[0][1] = __builtin_amdgcn_mfma_f32_16x16x32_f16(qa0[s], qb1[s], acc[0][1], 0, 0, 0); \
    acc[1][0] = __builtin_amdgcn_mfma_f32_16x16x32_f16(qa1[s], qb0[s], acc[1][0], 0, 0, 0); \
    acc[1][1] = __builtin_amdgcn_mfma_f32_16x16x32_f16(qa1[s], qb1[s], acc[1][1], 0, 0, 0); }

  LDT(0, 0)
  LDT(1, 1)
#pragma unroll
  for (int ct = 0; ct < 64; ct += 2) {
    MMT(0)
    if (ct + 2 < 64) LDT(ct + 2, 0)
    MMT(1)
    if (ct + 3 < 64) LDT(ct + 3, 1)
  }
#undef LDT
#undef MMT

  const float rv0 = rdsh[l15], rv1 = rdsh[16 + l15];

  f32x4 accY[2][2];  // the values that get frag-stored (MODE 0/1)

  if (MODE == 0) {
    // T -> Xs (raw, no activation yet)
#pragma unroll
    for (int df = 0; df < 2; ++df)
#pragma unroll
      for (int fi = 0; fi < 2; ++fi)
#pragma unroll
        for (int r = 0; r < 4; ++r)
          Xs[fi * 16 + l15][d0 + df * 16 + quad * 4 + r] = acc[df][fi][r];
    __syncthreads();
    // z = T @ W0
    f32x4 acc2[2][2] = {};
    epiGemm(Xs, WA, d0, quad, l15, acc2);
    __syncthreads();
    // act1 = relu((z + b0) * rd)
#pragma unroll
    for (int df = 0; df < 2; ++df)
#pragma unroll
      for (int fi = 0; fi < 2; ++fi)
#pragma unroll
        for (int r = 0; r < 4; ++r) {
          int d = d0 + df * 16 + quad * 4 + r;
          float rv = fi ? rv1 : rv0;
          Xs[fi * 16 + l15][d] = fmaxf((acc2[df][fi][r] + bsh[d]) * rv, 0.f);
        }
    __syncthreads();
    // Y1 = act1 @ W1
    f32x4 acc3[2][2] = {};
    epiGemm(Xs, WB, d0, quad, l15, acc3);
#pragma unroll
    for (int df = 0; df < 2; ++df)
#pragma unroll
      for (int fi = 0; fi < 2; ++fi) accY[df][fi] = acc3[df][fi];
  } else {
    // act = relu((acc + b) * rd)
#pragma unroll
    for (int df = 0; df < 2; ++df)
#pragma unroll
      for (int fi = 0; fi < 2; ++fi)
#pragma unroll
        for (int r = 0; r < 4; ++r) {
          int d = d0 + df * 16 + quad * 4 + r;
          float rv = fi ? rv1 : rv0;
          Xs[fi * 16 + l15][d] = fmaxf((acc[df][fi][r] + bsh[d]) * rv, 0.f);
        }
    __syncthreads();
    if (MODE == 2) {
      float* outB = out + (size_t)(batch * NN + i0) * DD;
#pragma unroll
      for (int u = 0; u < 4; ++u) {
        int c = tid + 256 * u;
        int i = c >> 5, f4 = (c & 31) * 4;
        *(float4*)(outB + (size_t)i * DD + f4) = *(const float4*)&Xs[i][f4];
      }
      return;
    }
    f32x4 acc2[2][2] = {};
    epiGemm(Xs, WA, d0, quad, l15, acc2);
#pragma unroll
    for (int df = 0; df < 2; ++df)
#pragma unroll
      for (int fi = 0; fi < 2; ++fi) accY[df][fi] = acc2[df][fi];
  }

  // frag-tiled store of accY -> Yout via LDS bounce (stride 40 fp16, 16B rows)
  __syncthreads();  // all Xs reads done before overlay
  _Float16* Yst = (_Float16*)Xs;
#pragma unroll
  for (int df = 0; df < 2; ++df)
#pragma unroll
    for (int fi = 0; fi < 2; ++fi)
#pragma unroll
      for (int r = 0; r < 4; ++r)
        Yst[(d0 + df * 16 + quad * 4 + r) * 40 + fi * 16 + l15] =
            (_Float16)accY[df][fi][r];
  __syncthreads();
  const int nt = i0 >> 5;
  _Float16* Yb = Yout + batA;
#pragma unroll
  for (int dtl = 0; dtl < 2; ++dtl) {
    const int dt = 2 * wave + dtl;
    f16x8 v = *(const f16x8*)(&Yst[(dt * 16 + l15) * 40 + quad * 8]);
    *(f16x8*)(Yb + ((size_t)(dt * 64 + nt)) * 512 + lane * 8) = v;
  }
}

// ===========================================================================
// Legacy path (round-0 proven) — fallback when workspace < 80 MB.
// ===========================================================================
__global__ __launch_bounds__(256) void gemmY_kernel(
    const float* __restrict__ X, const _Float16* __restrict__ Wt,
    _Float16* __restrict__ Yt) {
  const int bx = blockIdx.x;
  const int batch = bx & 7, n0 = (bx >> 3) * 32;
  const int tid = threadIdx.x, lane = tid & 63, wave = tid >> 6;
  const int quad = lane >> 4, l15 = lane & 15, d0 = wave * 32;
  const float* Xb = X + (size_t)(batch * NN + n0) * DD;
  f32x4 acc[2][2] = {};
#pragma unroll
  for (int kk = 0; kk < 128; kk += 32) {
    f16x8 a0 = *(const f16x8*)(Wt + (d0 + l15) * DD + kk + quad * 8);
    f16x8 a1 = *(const f16x8*)(Wt + (d0 + 16 + l15) * DD + kk + quad * 8);
#pragma unroll
    for (int fi = 0; fi < 2; ++fi) {
      const float* xp = Xb + (size_t)(fi * 16 + l15) * DD + kk + quad * 8;
      float4 x0 = *(const float4*)xp;
      float4 x1 = *(const float4*)(xp + 4);
      f16x8 b = {(_Float16)x0.x, (_Float16)x0.y, (_Float16)x0.z, (_Float16)x0.w,
                 (_Float16)x1.x, (_Float16)x1.y, (_Float16)x1.z, (_Float16)x1.w};
      acc[0][fi] = __builtin_amdgcn_mfma_f32_16x16x32_f16(a0, b, acc[0][fi], 0, 0, 0);
      acc[1][fi] = __builtin_amdgcn_mfma_f32_16x16x32_f16(a1, b, acc[1][fi], 0, 0, 0);
    }
  }
  _Float16* YtB = Yt + (size_t)batch * DD * NN;
#pragma unroll
  for (int df = 0; df < 2; ++df)
#pragma unroll
    for (int fi = 0; fi < 2; ++fi)
#pragma unroll
      for (int r = 0; r < 4; ++r)
        YtB[(size_t)(d0 + df * 16 + quad * 4 + r) * NN + n0 + fi * 16 + l15] =
            (_Float16)acc[df][fi][r];
}

template<bool LAST>
__global__ __launch_bounds__(256) void agg_kernel(
    const float* __restrict__ adj, const _Float16* __restrict__ Yt,
    const float* __restrict__ bias, const _Float16* __restrict__ Wn,
    _Float16* __restrict__ Ytn, float* __restrict__ out) {
  __shared__ _Float16 Bs[2][32 * 64];
  __shared__ float Xs[32][132];
  __shared__ float bsh[128];
  __shared__ float rd[32];

  const int tid = threadIdx.x, bx = blockIdx.x;
  const int batch = bx & 7, i0 = (bx >> 3) * 32;
  const int lane = tid & 63, wave = tid >> 6;
  const int quad = lane >> 4, l15 = lane & 15, d0 = wave * 32;
  const int ai = tid >> 3, ac = tid & 7;
  const int sc = ac ^ (ai & 7);

  const float* adjR = adj + (size_t)(batch * NN + i0 + ai) * NN + ac * 8;
  const _Float16* YtB = Yt + (size_t)batch * DD * NN;
  const _Float16* Ya0 = YtB + (size_t)(d0 + l15) * NN;
  const _Float16* Ya1 = YtB + (size_t)(d0 + 16 + l15) * NN;

  if (tid < 128) bsh[tid] = bias[tid];

  f32x4 acc[2][2] = {};
  float rowsum = 0.f;

  float4 av0 = *(const float4*)(adjR);
  float4 av1 = *(const float4*)(adjR + 4);
  f16x8 a[2][2];
#pragma unroll
  for (int k2 = 0; k2 < 2; ++k2) {
    a[k2][0] = *(const f16x8*)(Ya0 + k2 * 32 + quad * 8);
    a[k2][1] = *(const f16x8*)(Ya1 + k2 * 32 + quad * 8);
  }

  for (int ko = 0; ko < 32; ++ko) {
    rowsum += ((av0.x + av0.y) + (av0.z + av0.w)) + ((av1.x + av1.y) + (av1.z + av1.w));
    f16x8 h = {(_Float16)av0.x, (_Float16)av0.y, (_Float16)av0.z, (_Float16)av0.w,
               (_Float16)av1.x, (_Float16)av1.y, (_Float16)av1.z, (_Float16)av1.w};
    *(f16x8*)(&Bs[ko & 1][ai * 64 + sc * 8]) = h;
    f16x8 an[2][2];
    if (ko < 31) {
      const int kb = (ko + 1) * 64;
      av0 = *(const float4*)(adjR + kb);
      av1 = *(const float4*)(adjR + kb + 4);
#pragma unroll
      for (int k2 = 0; k2 < 2; ++k2) {
        an[k2][0] = *(const f16x8*)(Ya0 + kb + k2 * 32 + quad * 8);
        an[k2][1] = *(const f16x8*)(Ya1 + kb + k2 * 32 + quad * 8);
      }
    }
    __syncthreads();
    const _Float16* B = Bs[ko & 1];
#pragma unroll
    for (int k2 = 0; k2 < 2; ++k2)
#pragma unroll
      for (int fi = 0; fi < 2; ++fi) {
        const int row = fi * 16 + l15;
        const int ch = (k2 * 4 + quad) ^ (row & 7);
        f16x8 b = *(const f16x8*)(&B[row * 64 + ch * 8]);
        acc[0][fi] = __builtin_amdgcn_mfma_f32_16x16x32_f16(a[k2][0], b, acc[0][fi], 0, 0, 0);
        acc[1][fi] = __builtin_amdgcn_mfma_f32_16x16x32_f16(a[k2][1], b, acc[1][fi], 0, 0, 0);
      }
#pragma unroll
    for (int k2 = 0; k2 < 2; ++k2) { a[k2][0] = an[k2][0]; a[k2][1] = an[k2][1]; }
  }

  rowsum += __shfl_xor(rowsum, 1);
  rowsum += __shfl_xor(rowsum, 2);
  rowsum += __shfl_xor(rowsum, 4);
  if (ac == 0) rd[ai] = 1.0f / (rowsum + 1.0f);
  __syncthreads();

#pragma unroll
  for (int df = 0; df < 2; ++df)
#pragma unroll
    for (int fi = 0; fi < 2; ++fi)
#pragma unroll
      for (int r = 0; r < 4; ++r) {
        int d = d0 + df * 16 + quad * 4 + r;
        int i = fi * 16 + l15;
        Xs[i][d] = fmaxf((acc[df][fi][r] + bsh[d]) * rd[i], 0.f);
      }
  __syncthreads();

  if (LAST) {
    float* outB = out + (size_t)(batch * NN + i0) * DD;
#pragma unroll
    for (int u = 0; u < 4; ++u) {
      int c = tid + 256 * u;
      int i = c >> 5, f4 = (c & 31) * 4;
      *(float4*)(outB + (size_t)i * DD + f4) = *(const float4*)&Xs[i][f4];
    }
  } else {
    f32x4 acc2[2][2] = {};
    epiGemm(Xs, Wn, d0, quad, l15, acc2);
    _Float16* YnB = Ytn + (size_t)batch * DD * NN;
#pragma unroll
    for (int df = 0; df < 2; ++df)
#pragma unroll
      for (int fi = 0; fi < 2; ++fi)
#pragma unroll
        for (int r = 0; r < 4; ++r)
          YnB[(size_t)(d0 + df * 16 + quad * 4 + r) * NN + i0 + fi * 16 + l15] =
              (_Float16)acc2[df][fi][r];
  }
}

extern "C" void kernel_launch(void* const* d_in, const int* in_sizes, int n_in,
                              void* d_out, int out_size, void* d_ws, size_t ws_size,
                              hipStream_t stream) {
  const float* x0   = (const float*)d_in[0];   // [8,2048,128]
  const float* adj  = (const float*)d_in[1];   // [8,2048,2048]
  const float* W    = (const float*)d_in[2];   // [3,128,128]
  const float* bias = (const float*)d_in[3];   // [3,128]
  float* out = (float*)d_out;

  _Float16* Wt   = (_Float16*)d_ws;                             // 96 KB
  float*    rdg  = (float*)((char*)d_ws + (1u << 17));          // 64 KB
  _Float16* Xt   = (_Float16*)((char*)d_ws + (1u << 20));       // 4 MiB
  _Float16* Y1t  = (_Float16*)((char*)d_ws + (5u << 20));       // 4 MiB
  _Float16* Y2t  = (_Float16*)((char*)d_ws + (9u << 20));       // 4 MiB
  _Float16* adjH = (_Float16*)((char*)d_ws + (16u << 20));      // 64 MiB

  const bool big = ws_size >= (80ull << 20);

  dim3 blk(256);
  prep_kernel<<<192, blk, 0, stream>>>(W, Wt);
  if (big) {
    prepAdj_kernel  <<<1024, blk, 0, stream>>>(adj, adjH, rdg);
    transposeX_kernel<<<512, blk, 0, stream>>>(x0, Xt);
    // layer 1 (W0 folded into epilogue, + fused layer-2 Linear)
    aggT_kernel<0><<<512, blk, 0, stream>>>(adjH, rdg, Xt, bias, Wt, Wt + 16384, Y1t, nullptr);
    // layer 2 (+ fused layer-3 Linear)
    aggT_kernel<1><<<512, blk, 0, stream>>>(adjH, rdg, Y1t, bias + 128, Wt + 32768, nullptr, Y2t, nullptr);
    // layer 3 -> fp32 out
    aggT_kernel<2><<<512, blk, 0, stream>>>(adjH, rdg, Y2t, bias + 256, nullptr, nullptr, nullptr, out);
  } else {
    _Float16* YtA  = Xt;
    _Float16* YtB_ = (_Float16*)d_out;
    gemmY_kernel<<<512, blk, 0, stream>>>(x0, Wt, YtA);
    agg_kernel<false><<<512, blk, 0, stream>>>(adj, YtA,  bias,       Wt + 16384, YtB_, nullptr);
    agg_kernel<false><<<512, blk, 0, stream>>>(adj, YtB_, bias + 128, Wt + 32768, YtA,  nullptr);
    agg_kernel<true ><<<512, blk, 0, stream>>>(adj, YtA,  bias + 256, nullptr,    nullptr, out);
  }
}

// Round 4
// 294.386 us; speedup vs baseline: 1.1898x; 1.0002x over previous
//
#include <hip/hip_runtime.h>

#define NN 2048
#define DD 128

typedef _Float16 f16x8 __attribute__((ext_vector_type(8)));
typedef float f32x4 __attribute__((ext_vector_type(4)));

// ===========================================================================
// Fragment-tiled fp16 layout for 16x16x32 MFMA operands, matrix [R][C]:
//   tile (rt, ct) = rows rt*16..+16, cols ct*32..+32, stored as 512 fp16 at
//   blockbase = (rt*(C/32) + ct)*512; element lane*8+e holds
//   M[rt*16 + (lane&15)][ct*32 + (lane>>4)*8 + e].
// Every wave frag load/store = contiguous 1 KB.
// ===========================================================================

// ---------------------------------------------------------------------------
// prep: Wt[l][d][k] = fp16(W[l][k][d])  (3 layers, 48K elems — trivial)
// Used by BOTH paths; fallback path touches nothing beyond Wt (96 KB).
// ---------------------------------------------------------------------------
__global__ __launch_bounds__(256) void prep_kernel(
    const float* __restrict__ W, _Float16* __restrict__ Wt) {
  int idx = blockIdx.x * 256 + threadIdx.x;
  int l = idx >> 14, r = idx & 16383, d = r >> 7, k = r & 127;
  Wt[idx] = (_Float16)W[l * 16384 + k * 128 + d];
}

// ---------------------------------------------------------------------------
// prepAll (big path only): adj fp32 -> frag-tiled fp16 adjH + rdg; X -> Xt.
//   bx <1024 : adjH + rdg     bx <1536 : Xt
// ---------------------------------------------------------------------------
__global__ __launch_bounds__(256) void prepAll_kernel(
    const float* __restrict__ adj, _Float16* __restrict__ adjH,
    float* __restrict__ rdg, const float* __restrict__ X,
    _Float16* __restrict__ Xt) {
  __shared__ float rs[16][4];
  const int bx = blockIdx.x, tid = threadIdx.x;
  const int lane = tid & 63, wave = tid >> 6;
  const int quad = lane >> 4, l15 = lane & 15;

  if (bx < 1024) {
    // ---- prepAdj: batch = bx>>7, row-tile of 16 = bx&127
    const int it = bx & 127, batch = bx >> 7;
    const float* Ap = adj + ((size_t)(batch * NN) + it * 16 + l15) * NN + quad * 8;
    _Float16* Hp = adjH + (size_t)batch * NN * NN + ((size_t)it * 64) * 512 + lane * 8;
    float s = 0.f;
#pragma unroll
    for (int j = 0; j < 16; ++j) {
      const int ct = wave + 4 * j;
      float4 a0 = *(const float4*)(Ap + ct * 32);
      float4 a1 = *(const float4*)(Ap + ct * 32 + 4);
      s += ((a0.x + a0.y) + (a0.z + a0.w)) + ((a1.x + a1.y) + (a1.z + a1.w));
      f16x8 h = {(_Float16)a0.x, (_Float16)a0.y, (_Float16)a0.z, (_Float16)a0.w,
                 (_Float16)a1.x, (_Float16)a1.y, (_Float16)a1.z, (_Float16)a1.w};
      *(f16x8*)(Hp + (size_t)ct * 512) = h;
    }
    s += __shfl_xor(s, 16);
    s += __shfl_xor(s, 32);
    if (lane < 16) rs[lane][wave] = s;
    __syncthreads();
    if (tid < 16) {
      float t = rs[tid][0] + rs[tid][1] + rs[tid][2] + rs[tid][3];
      rdg[batch * NN + it * 16 + tid] = 1.0f / (t + 1.0f);
    }
  } else if (bx < 1536) {
    // ---- transposeX: batch = vbx&7, n-tile of 32 = vbx>>3
    const int vbx = bx - 1024;
    const int batch = vbx & 7, nt = vbx >> 3;
    const size_t batA = (size_t)batch * (128 * NN);
#pragma unroll
    for (int dtl = 0; dtl < 2; ++dtl) {
      const int dt = wave * 2 + dtl;
      const float* Xp = X + ((size_t)(batch * NN) + nt * 32 + quad * 8) * DD + dt * 16 + l15;
      f16x8 v;
#pragma unroll
      for (int e = 0; e < 8; ++e) v[e] = (_Float16)Xp[(size_t)e * DD];
      *(f16x8*)(Xt + batA + ((size_t)(dt * 64 + nt)) * 512 + lane * 8) = v;
    }
  }
}

// ---------------------------------------------------------------------------
// epilogue helper: o[dout][i] += sum_k Wf-frag[dout][k] * fp16(Xs[i][k])
// ---------------------------------------------------------------------------
__device__ __forceinline__ void epiGemm(const float (*Xs)[132],
    const _Float16* __restrict__ Wf, int d0, int quad, int l15,
    f32x4 (&o)[2][2]) {
#pragma unroll
  for (int kk = 0; kk < 128; kk += 32) {
    f16x8 a0 = *(const f16x8*)(Wf + (d0 + l15) * DD + kk + quad * 8);
    f16x8 a1 = *(const f16x8*)(Wf + (d0 + 16 + l15) * DD + kk + quad * 8);
#pragma unroll
    for (int fi = 0; fi < 2; ++fi) {
      const float* xp = &Xs[fi * 16 + l15][kk + quad * 8];
      f16x8 b = {(_Float16)xp[0], (_Float16)xp[1], (_Float16)xp[2], (_Float16)xp[3],
                 (_Float16)xp[4], (_Float16)xp[5], (_Float16)xp[6], (_Float16)xp[7]};
      o[0][fi] = __builtin_amdgcn_mfma_f32_16x16x32_f16(a0, b, o[0][fi], 0, 0, 0);
      o[1][fi] = __builtin_amdgcn_mfma_f32_16x16x32_f16(a1, b, o[1][fi], 0, 0, 0);
    }
  }
}

// ---------------------------------------------------------------------------
// aggL: GCN layer. acc[d][i] = sum_n At[d][n] * adjH[i][n].
// A: per-wave coalesced frag stream from global (one batch per XCD -> L2).
// B: staged ONCE per block into LDS (2 KB/ct, double-buffered, 1 barrier/ct)
//    and shared by all 4 waves — no redundant B fetch.
// MODE 0: epi = T@W0 -> +b,*rd,relu -> @W1 -> frag-store Yout
// MODE 1: epi = +b,*rd,relu -> @WA -> frag-store Yout
// MODE 2: epi = +b,*rd,relu -> fp32 out
// ---------------------------------------------------------------------------
template<int MODE>
__global__ __launch_bounds__(256) void aggL_kernel(
    const _Float16* __restrict__ adjH, const float* __restrict__ rdg,
    const _Float16* __restrict__ At, const float* __restrict__ bias,
    const _Float16* __restrict__ WA, const _Float16* __restrict__ WB,
    _Float16* __restrict__ Yout, float* __restrict__ out) {
  __shared__ _Float16 Bs[2][1024];   // 2 x (2 frag-tiles of 1 KB)
  __shared__ float Xs[32][132];
  __shared__ float bsh[128];
  __shared__ float rdsh[32];

  const int tid = threadIdx.x, bx = blockIdx.x;
  const int batch = bx & 7, iblk = bx >> 3, i0 = iblk * 32;
  const int lane = tid & 63, wave = tid >> 6;
  const int quad = lane >> 4, l15 = lane & 15, d0 = wave * 32;

  const size_t batA = (size_t)batch * (128 * NN);
  const size_t batB = (size_t)batch * ((size_t)NN * NN);
  const _Float16* Ap0 = At + batA + ((size_t)(2 * wave) * 64) * 512 + lane * 8;
  const _Float16* Ap1 = At + batA + ((size_t)(2 * wave + 1) * 64) * 512 + lane * 8;
  const _Float16* BpW = adjH + batB + ((size_t)(iblk * 2 + wave) * 64) * 512 + lane * 8;

  if (tid < 128) bsh[tid] = bias[tid];
  if (tid < 32) rdsh[tid] = rdg[batch * NN + i0 + tid];

  // prologue: stage B(0), prefetch A(0)
  if (wave < 2) {
    f16x8 h0 = *(const f16x8*)(BpW);
    *(f16x8*)&Bs[0][wave * 512 + lane * 8] = h0;
  }
  f16x8 aC0 = *(const f16x8*)(Ap0);
  f16x8 aC1 = *(const f16x8*)(Ap1);
  f32x4 acc[2][2] = {};
  __syncthreads();

#define STEP(ct, CB, NB)                                                                   \
  {                                                                                        \
    const bool stg = (wave < 2) && ((ct) < 63);                                            \
    f16x8 hN = {};                                                                         \
    if (stg) hN = *(const f16x8*)(BpW + ((ct) + 1) * 512);                                 \
    const int ctn = ((ct) < 63) ? (ct) + 1 : (ct);                                         \
    f16x8 aN0 = *(const f16x8*)(Ap0 + ctn * 512);                                          \
    f16x8 aN1 = *(const f16x8*)(Ap1 + ctn * 512);                                          \
    f16x8 b0 = *(const f16x8*)&Bs[CB][lane * 8];                                           \
    f16x8 b1 = *(const f16x8*)&Bs[CB][512 + lane * 8];                                     \
    acc[0][0] = __builtin_amdgcn_mfma_f32_16x16x32_f16(aC0, b0, acc[0][0], 0, 0, 0);       \
    acc[0][1] = __builtin_amdgcn_mfma_f32_16x16x32_f16(aC0, b1, acc[0][1], 0, 0, 0);       \
    acc[1][0] = __builtin_amdgcn_mfma_f32_16x16x32_f16(aC1, b0, acc[1][0], 0, 0, 0);       \
    acc[1][1] = __builtin_amdgcn_mfma_f32_16x16x32_f16(aC1, b1, acc[1][1], 0, 0, 0);       \
    if (stg) *(f16x8*)&Bs[NB][wave * 512 + lane * 8] = hN;                                 \
    __syncthreads();                                                                       \
    aC0 = aN0;                                                                             \
    aC1 = aN1;                                                                             \
  }

  for (int ct = 0; ct < 64; ct += 2) {
    STEP(ct, 0, 1)
    STEP(ct + 1, 1, 0)
  }
#undef STEP

  const float rv0 = rdsh[l15], rv1 = rdsh[16 + l15];
  f32x4 accY[2][2];

  if (MODE == 0) {
    // T -> Xs raw
#pragma unroll
    for (int df = 0; df < 2; ++df)
#pragma unroll
      for (int fi = 0; fi < 2; ++fi)
#pragma unroll
        for (int r = 0; r < 4; ++r)
          Xs[fi * 16 + l15][d0 + df * 16 + quad * 4 + r] = acc[df][fi][r];
    __syncthreads();
    f32x4 acc2[2][2] = {};
    epiGemm(Xs, WA, d0, quad, l15, acc2);
    __syncthreads();
#pragma unroll
    for (int df = 0; df < 2; ++df)
#pragma unroll
      for (int fi = 0; fi < 2; ++fi)
#pragma unroll
        for (int r = 0; r < 4; ++r) {
          int d = d0 + df * 16 + quad * 4 + r;
          float rv = fi ? rv1 : rv0;
          Xs[fi * 16 + l15][d] = fmaxf((acc2[df][fi][r] + bsh[d]) * rv, 0.f);
        }
    __syncthreads();
    f32x4 acc3[2][2] = {};
    epiGemm(Xs, WB, d0, quad, l15, acc3);
#pragma unroll
    for (int df = 0; df < 2; ++df)
#pragma unroll
      for (int fi = 0; fi < 2; ++fi) accY[df][fi] = acc3[df][fi];
  } else {
#pragma unroll
    for (int df = 0; df < 2; ++df)
#pragma unroll
      for (int fi = 0; fi < 2; ++fi)
#pragma unroll
        for (int r = 0; r < 4; ++r) {
          int d = d0 + df * 16 + quad * 4 + r;
          float rv = fi ? rv1 : rv0;
          Xs[fi * 16 + l15][d] = fmaxf((acc[df][fi][r] + bsh[d]) * rv, 0.f);
        }
    __syncthreads();
    if (MODE == 2) {
      float* outB = out + (size_t)(batch * NN + i0) * DD;
#pragma unroll
      for (int u = 0; u < 4; ++u) {
        int c = tid + 256 * u;
        int i = c >> 5, f4 = (c & 31) * 4;
        *(float4*)(outB + (size_t)i * DD + f4) = *(const float4*)&Xs[i][f4];
      }
      return;
    }
    f32x4 acc2[2][2] = {};
    epiGemm(Xs, WA, d0, quad, l15, acc2);
#pragma unroll
    for (int df = 0; df < 2; ++df)
#pragma unroll
      for (int fi = 0; fi < 2; ++fi) accY[df][fi] = acc2[df][fi];
  }

  // frag-tiled store of accY via LDS bounce
  __syncthreads();
  _Float16* Yst = (_Float16*)Xs;
#pragma unroll
  for (int df = 0; df < 2; ++df)
#pragma unroll
    for (int fi = 0; fi < 2; ++fi)
#pragma unroll
      for (int r = 0; r < 4; ++r)
        Yst[(d0 + df * 16 + quad * 4 + r) * 40 + fi * 16 + l15] =
            (_Float16)accY[df][fi][r];
  __syncthreads();
  const int nt = i0 >> 5;
  _Float16* Yb = Yout + batA;
#pragma unroll
  for (int dtl = 0; dtl < 2; ++dtl) {
    const int dt = 2 * wave + dtl;
    f16x8 v = *(const f16x8*)(&Yst[(dt * 16 + l15) * 40 + quad * 8]);
    *(f16x8*)(Yb + ((size_t)(dt * 64 + nt)) * 512 + lane * 8) = v;
  }
}

// ===========================================================================
// Legacy fallback (round-0 proven) — used when workspace < 81 MB.
// Touches only Wt (96 KB) + YtA (4 MiB at +1 MiB) in workspace.
// ===========================================================================
__global__ __launch_bounds__(256) void gemmY_kernel(
    const float* __restrict__ X, const _Float16* __restrict__ Wt,
    _Float16* __restrict__ Yt) {
  const int bx = blockIdx.x;
  const int batch = bx & 7, n0 = (bx >> 3) * 32;
  const int tid = threadIdx.x, lane = tid & 63, wave = tid >> 6;
  const int quad = lane >> 4, l15 = lane & 15, d0 = wave * 32;
  const float* Xb = X + (size_t)(batch * NN + n0) * DD;
  f32x4 acc[2][2] = {};
#pragma unroll
  for (int kk = 0; kk < 128; kk += 32) {
    f16x8 a0 = *(const f16x8*)(Wt + (d0 + l15) * DD + kk + quad * 8);
    f16x8 a1 = *(const f16x8*)(Wt + (d0 + 16 + l15) * DD + kk + quad * 8);
#pragma unroll
    for (int fi = 0; fi < 2; ++fi) {
      const float* xp = Xb + (size_t)(fi * 16 + l15) * DD + kk + quad * 8;
      float4 x0 = *(const float4*)xp;
      float4 x1 = *(const float4*)(xp + 4);
      f16x8 b = {(_Float16)x0.x, (_Float16)x0.y, (_Float16)x0.z, (_Float16)x0.w,
                 (_Float16)x1.x, (_Float16)x1.y, (_Float16)x1.z, (_Float16)x1.w};
      acc[0][fi] = __builtin_amdgcn_mfma_f32_16x16x32_f16(a0, b, acc[0][fi], 0, 0, 0);
      acc[1][fi] = __builtin_amdgcn_mfma_f32_16x16x32_f16(a1, b, acc[1][fi], 0, 0, 0);
    }
  }
  _Float16* YtB = Yt + (size_t)batch * DD * NN;
#pragma unroll
  for (int df = 0; df < 2; ++df)
#pragma unroll
    for (int fi = 0; fi < 2; ++fi)
#pragma unroll
      for (int r = 0; r < 4; ++r)
        YtB[(size_t)(d0 + df * 16 + quad * 4 + r) * NN + n0 + fi * 16 + l15] =
            (_Float16)acc[df][fi][r];
}

template<bool LAST>
__global__ __launch_bounds__(256) void agg_kernel(
    const float* __restrict__ adj, const _Float16* __restrict__ Yt,
    const float* __restrict__ bias, const _Float16* __restrict__ Wn,
    _Float16* __restrict__ Ytn, float* __restrict__ out) {
  __shared__ _Float16 Bsl[2][32 * 64];
  __shared__ float Xs[32][132];
  __shared__ float bsh[128];
  __shared__ float rd[32];

  const int tid = threadIdx.x, bx = blockIdx.x;
  const int batch = bx & 7, i0 = (bx >> 3) * 32;
  const int lane = tid & 63, wave = tid >> 6;
  const int quad = lane >> 4, l15 = lane & 15, d0 = wave * 32;
  const int ai = tid >> 3, ac = tid & 7;
  const int sc = ac ^ (ai & 7);

  const float* adjR = adj + (size_t)(batch * NN + i0 + ai) * NN + ac * 8;
  const _Float16* YtB = Yt + (size_t)batch * DD * NN;
  const _Float16* Ya0 = YtB + (size_t)(d0 + l15) * NN;
  const _Float16* Ya1 = YtB + (size_t)(d0 + 16 + l15) * NN;

  if (tid < 128) bsh[tid] = bias[tid];

  f32x4 acc[2][2] = {};
  float rowsum = 0.f;

  float4 av0 = *(const float4*)(adjR);
  float4 av1 = *(const float4*)(adjR + 4);
  f16x8 a[2][2];
#pragma unroll
  for (int k2 = 0; k2 < 2; ++k2) {
    a[k2][0] = *(const f16x8*)(Ya0 + k2 * 32 + quad * 8);
    a[k2][1] = *(const f16x8*)(Ya1 + k2 * 32 + quad * 8);
  }

  for (int ko = 0; ko < 32; ++ko) {
    rowsum += ((av0.x + av0.y) + (av0.z + av0.w)) + ((av1.x + av1.y) + (av1.z + av1.w));
    f16x8 h = {(_Float16)av0.x, (_Float16)av0.y, (_Float16)av0.z, (_Float16)av0.w,
               (_Float16)av1.x, (_Float16)av1.y, (_Float16)av1.z, (_Float16)av1.w};
    *(f16x8*)(&Bsl[ko & 1][ai * 64 + sc * 8]) = h;
    f16x8 an[2][2];
    if (ko < 31) {
      const int kb = (ko + 1) * 64;
      av0 = *(const float4*)(adjR + kb);
      av1 = *(const float4*)(adjR + kb + 4);
#pragma unroll
      for (int k2 = 0; k2 < 2; ++k2) {
        an[k2][0] = *(const f16x8*)(Ya0 + kb + k2 * 32 + quad * 8);
        an[k2][1] = *(const f16x8*)(Ya1 + kb + k2 * 32 + quad * 8);
      }
    }
    __syncthreads();
    const _Float16* B = Bsl[ko & 1];
#pragma unroll
    for (int k2 = 0; k2 < 2; ++k2)
#pragma unroll
      for (int fi = 0; fi < 2; ++fi) {
        const int row = fi * 16 + l15;
        const int ch = (k2 * 4 + quad) ^ (row & 7);
        f16x8 b = *(const f16x8*)(&B[row * 64 + ch * 8]);
        acc[0][fi] = __builtin_amdgcn_mfma_f32_16x16x32_f16(a[k2][0], b, acc[0][fi], 0, 0, 0);
        acc[1][fi] = __builtin_amdgcn_mfma_f32_16x16x32_f16(a[k2][1], b, acc[1][fi], 0, 0, 0);
      }
#pragma unroll
    for (int k2 = 0; k2 < 2; ++k2) { a[k2][0] = an[k2][0]; a[k2][1] = an[k2][1]; }
  }

  rowsum += __shfl_xor(rowsum, 1);
  rowsum += __shfl_xor(rowsum, 2);
  rowsum += __shfl_xor(rowsum, 4);
  if (ac == 0) rd[ai] = 1.0f / (rowsum + 1.0f);
  __syncthreads();

#pragma unroll
  for (int df = 0; df < 2; ++df)
#pragma unroll
    for (int fi = 0; fi < 2; ++fi)
#pragma unroll
      for (int r = 0; r < 4; ++r) {
        int d = d0 + df * 16 + quad * 4 + r;
        int i = fi * 16 + l15;
        Xs[i][d] = fmaxf((acc[df][fi][r] + bsh[d]) * rd[i], 0.f);
      }
  __syncthreads();

  if (LAST) {
    float* outB = out + (size_t)(batch * NN + i0) * DD;
#pragma unroll
    for (int u = 0; u < 4; ++u) {
      int c = tid + 256 * u;
      int i = c >> 5, f4 = (c & 31) * 4;
      *(float4*)(outB + (size_t)i * DD + f4) = *(const float4*)&Xs[i][f4];
    }
  } else {
    f32x4 acc2[2][2] = {};
    epiGemm(Xs, Wn, d0, quad, l15, acc2);
    _Float16* YnB = Ytn + (size_t)batch * DD * NN;
#pragma unroll
    for (int df = 0; df < 2; ++df)
#pragma unroll
      for (int fi = 0; fi < 2; ++fi)
#pragma unroll
        for (int r = 0; r < 4; ++r)
          YnB[(size_t)(d0 + df * 16 + quad * 4 + r) * NN + i0 + fi * 16 + l15] =
              (_Float16)acc2[df][fi][r];
  }
}

extern "C" void kernel_launch(void* const* d_in, const int* in_sizes, int n_in,
                              void* d_out, int out_size, void* d_ws, size_t ws_size,
                              hipStream_t stream) {
  const float* x0   = (const float*)d_in[0];   // [8,2048,128]
  const float* adj  = (const float*)d_in[1];   // [8,2048,2048]
  const float* W    = (const float*)d_in[2];   // [3,128,128]
  const float* bias = (const float*)d_in[3];   // [3,128]
  float* out = (float*)d_out;

  _Float16* Wt   = (_Float16*)d_ws;                             // 96 KB
  float*    rdg  = (float*)((char*)d_ws + (1u << 17));          // 64 KB
  _Float16* Xt   = (_Float16*)((char*)d_ws + (1u << 20));       // 4 MiB
  _Float16* Y1t  = (_Float16*)((char*)d_ws + (5u << 20));       // 4 MiB
  _Float16* Y2t  = (_Float16*)((char*)d_ws + (9u << 20));       // 4 MiB
  _Float16* adjH = (_Float16*)((char*)d_ws + (16u << 20));      // 64 MiB ends at 80 MiB

  const bool big = ws_size >= (81ull << 20);

  dim3 blk(256);
  prep_kernel<<<192, blk, 0, stream>>>(W, Wt);
  if (big) {
    prepAll_kernel<<<1536, blk, 0, stream>>>(adj, adjH, rdg, x0, Xt);
    // layer 1 (W0 folded into epilogue, + fused layer-2 Linear)
    aggL_kernel<0><<<512, blk, 0, stream>>>(adjH, rdg, Xt, bias, Wt, Wt + 16384, Y1t, nullptr);
    // layer 2 (+ fused layer-3 Linear)
    aggL_kernel<1><<<512, blk, 0, stream>>>(adjH, rdg, Y1t, bias + 128, Wt + 32768, nullptr, Y2t, nullptr);
    // layer 3 -> fp32 out
    aggL_kernel<2><<<512, blk, 0, stream>>>(adjH, rdg, Y2t, bias + 256, nullptr, nullptr, nullptr, out);
  } else {
    // self-contained legacy path: only Wt + YtA in workspace, d_out as scratch
    _Float16* YtA  = Xt;
    _Float16* YtB_ = (_Float16*)d_out;
    gemmY_kernel<<<512, blk, 0, stream>>>(x0, Wt, YtA);
    agg_kernel<false><<<512, blk, 0, stream>>>(adj, YtA,  bias,       Wt + 16384, YtB_, nullptr);
    agg_kernel<false><<<512, blk, 0, stream>>>(adj, YtB_, bias + 128, Wt + 32768, YtA,  nullptr);
    agg_kernel<true ><<<512, blk, 0, stream>>>(adj, YtA,  bias + 256, nullptr,    nullptr, out);
  }
}

// Round 6
// 290.595 us; speedup vs baseline: 1.2053x; 1.0130x over previous
//
#include <hip/hip_runtime.h>

#define NN 2048
#define DD 128

typedef _Float16 f16x8 __attribute__((ext_vector_type(8)));
typedef float f32x4 __attribute__((ext_vector_type(4)));

// ===========================================================================
// Fragment-tiled fp16 layout for 16x16x32 MFMA operands, matrix [R][C]:
//   tile (rt, ct) = rows rt*16..+16, cols ct*32..+32, stored as 512 fp16 at
//   blockbase = (rt*(C/32) + ct)*512; element lane*8+e holds
//   M[rt*16 + (lane&15)][ct*32 + (lane>>4)*8 + e].
// Every wave frag load/store = contiguous 1 KB.
// ===========================================================================

// ---------------------------------------------------------------------------
// prep: Wt[l][d][k] = fp16(W[l][k][d])  (3 layers, 48K elems — trivial)
// ---------------------------------------------------------------------------
__global__ __launch_bounds__(256) void prep_kernel(
    const float* __restrict__ W, _Float16* __restrict__ Wt) {
  int idx = blockIdx.x * 256 + threadIdx.x;
  int l = idx >> 14, r = idx & 16383, d = r >> 7, k = r & 127;
  Wt[idx] = (_Float16)W[l * 16384 + k * 128 + d];
}

// ---------------------------------------------------------------------------
// prepAll (big path only): adj fp32 -> frag-tiled fp16 adjH + rdg; X -> Xt.
//   bx <1024 : adjH + rdg     bx <1536 : Xt
// ---------------------------------------------------------------------------
__global__ __launch_bounds__(256) void prepAll_kernel(
    const float* __restrict__ adj, _Float16* __restrict__ adjH,
    float* __restrict__ rdg, const float* __restrict__ X,
    _Float16* __restrict__ Xt) {
  __shared__ float rs[16][4];
  const int bx = blockIdx.x, tid = threadIdx.x;
  const int lane = tid & 63, wave = tid >> 6;
  const int quad = lane >> 4, l15 = lane & 15;

  if (bx < 1024) {
    const int it = bx & 127, batch = bx >> 7;
    const float* Ap = adj + ((size_t)(batch * NN) + it * 16 + l15) * NN + quad * 8;
    _Float16* Hp = adjH + (size_t)batch * NN * NN + ((size_t)it * 64) * 512 + lane * 8;
    float s = 0.f;
#pragma unroll
    for (int j = 0; j < 16; ++j) {
      const int ct = wave + 4 * j;
      float4 a0 = *(const float4*)(Ap + ct * 32);
      float4 a1 = *(const float4*)(Ap + ct * 32 + 4);
      s += ((a0.x + a0.y) + (a0.z + a0.w)) + ((a1.x + a1.y) + (a1.z + a1.w));
      f16x8 h = {(_Float16)a0.x, (_Float16)a0.y, (_Float16)a0.z, (_Float16)a0.w,
                 (_Float16)a1.x, (_Float16)a1.y, (_Float16)a1.z, (_Float16)a1.w};
      *(f16x8*)(Hp + (size_t)ct * 512) = h;
    }
    s += __shfl_xor(s, 16);
    s += __shfl_xor(s, 32);
    if (lane < 16) rs[lane][wave] = s;
    __syncthreads();
    if (tid < 16) {
      float t = rs[tid][0] + rs[tid][1] + rs[tid][2] + rs[tid][3];
      rdg[batch * NN + it * 16 + tid] = 1.0f / (t + 1.0f);
    }
  } else if (bx < 1536) {
    const int vbx = bx - 1024;
    const int batch = vbx & 7, nt = vbx >> 3;
    const size_t batA = (size_t)batch * (128 * NN);
#pragma unroll
    for (int dtl = 0; dtl < 2; ++dtl) {
      const int dt = wave * 2 + dtl;
      const float* Xp = X + ((size_t)(batch * NN) + nt * 32 + quad * 8) * DD + dt * 16 + l15;
      f16x8 v;
#pragma unroll
      for (int e = 0; e < 8; ++e) v[e] = (_Float16)Xp[(size_t)e * DD];
      *(f16x8*)(Xt + batA + ((size_t)(dt * 64 + nt)) * 512 + lane * 8) = v;
    }
  }
}

// ---------------------------------------------------------------------------
// epilogue helper: o[dout][i] += sum_k Wf-frag[dout][k] * fp16(Xs[i][k])
// ---------------------------------------------------------------------------
__device__ __forceinline__ void epiGemm(const float (*Xs)[132],
    const _Float16* __restrict__ Wf, int d0, int quad, int l15,
    f32x4 (&o)[2][2]) {
#pragma unroll
  for (int kk = 0; kk < 128; kk += 32) {
    f16x8 a0 = *(const f16x8*)(Wf + (d0 + l15) * DD + kk + quad * 8);
    f16x8 a1 = *(const f16x8*)(Wf + (d0 + 16 + l15) * DD + kk + quad * 8);
#pragma unroll
    for (int fi = 0; fi < 2; ++fi) {
      const float* xp = &Xs[fi * 16 + l15][kk + quad * 8];
      f16x8 b = {(_Float16)xp[0], (_Float16)xp[1], (_Float16)xp[2], (_Float16)xp[3],
                 (_Float16)xp[4], (_Float16)xp[5], (_Float16)xp[6], (_Float16)xp[7]};
      o[0][fi] = __builtin_amdgcn_mfma_f32_16x16x32_f16(a0, b, o[0][fi], 0, 0, 0);
      o[1][fi] = __builtin_amdgcn_mfma_f32_16x16x32_f16(a1, b, o[1][fi], 0, 0, 0);
    }
  }
}

// ---------------------------------------------------------------------------
// aggP: GCN layer, DEPTH-8 barrier-free register pipeline.
// acc[d][i] = sum_n At[d][n] * adjH[i][n], both frag-tiled (1 KB wave loads).
// Circular reg buffers q*[8], fully unrolled (static indices -> no scratch).
// ORDER: MM(ct) consumes slot ct&7 FIRST, then PF(ct+PD) refills it —
// (round-5 bug was the reverse: PF overwrote the slot MM was about to read).
// At MM(ct) issue, tiles ct+1..ct+7 (28 loads) remain in flight -> hipcc
// emits counted vmcnt, no drain-to-0, no barriers in the loop.
// MODE 0: epi = T@W0 -> +b,*rd,relu -> @W1 -> frag-store Yout
// MODE 1: epi = +b,*rd,relu -> @WA -> frag-store Yout
// MODE 2: epi = +b,*rd,relu -> fp32 out
// ---------------------------------------------------------------------------
#define PD 8

template<int MODE>
__global__ __launch_bounds__(256) void aggP_kernel(
    const _Float16* __restrict__ adjH, const float* __restrict__ rdg,
    const _Float16* __restrict__ At, const float* __restrict__ bias,
    const _Float16* __restrict__ WA, const _Float16* __restrict__ WB,
    _Float16* __restrict__ Yout, float* __restrict__ out) {
  __shared__ float Xs[32][132];
  __shared__ float bsh[128];
  __shared__ float rdsh[32];

  const int tid = threadIdx.x, bx = blockIdx.x;
  const int batch = bx & 7, iblk = bx >> 3, i0 = iblk * 32;
  const int lane = tid & 63, wave = tid >> 6;
  const int quad = lane >> 4, l15 = lane & 15, d0 = wave * 32;

  const size_t batA = (size_t)batch * (128 * NN);
  const size_t batB = (size_t)batch * ((size_t)NN * NN);
  const int it0 = iblk * 2;
  const _Float16* Ap0 = At + batA + ((size_t)(2 * wave) * 64) * 512 + lane * 8;
  const _Float16* Ap1 = At + batA + ((size_t)(2 * wave + 1) * 64) * 512 + lane * 8;
  const _Float16* Bp0 = adjH + batB + ((size_t)it0 * 64) * 512 + lane * 8;
  const _Float16* Bp1 = adjH + batB + ((size_t)(it0 + 1) * 64) * 512 + lane * 8;

  if (tid < 128) bsh[tid] = bias[tid];
  if (tid < 32) rdsh[tid] = rdg[batch * NN + i0 + tid];

  f32x4 acc[2][2] = {};
  f16x8 qa0[PD], qa1[PD], qb0[PD], qb1[PD];

#define PF(j)                                              \
  { const int s_ = (j) & (PD - 1);                         \
    qa0[s_] = *(const f16x8*)(Ap0 + (size_t)(j) * 512);    \
    qa1[s_] = *(const f16x8*)(Ap1 + (size_t)(j) * 512);    \
    qb0[s_] = *(const f16x8*)(Bp0 + (size_t)(j) * 512);    \
    qb1[s_] = *(const f16x8*)(Bp1 + (size_t)(j) * 512); }
#define MM(j)                                                                                   \
  { const int s_ = (j) & (PD - 1);                                                              \
    acc[0][0] = __builtin_amdgcn_mfma_f32_16x16x32_f16(qa0[s_], qb0[s_], acc[0][0], 0, 0, 0);   \
    acc[0][1] = __builtin_amdgcn_mfma_f32_16x16x32_f16(qa0[s_], qb1[s_], acc[0][1], 0, 0, 0);   \
    acc[1][0] = __builtin_amdgcn_mfma_f32_16x16x32_f16(qa1[s_], qb0[s_], acc[1][0], 0, 0, 0);   \
    acc[1][1] = __builtin_amdgcn_mfma_f32_16x16x32_f16(qa1[s_], qb1[s_], acc[1][1], 0, 0, 0); }

#pragma unroll
  for (int j = 0; j < PD; ++j) PF(j)
#pragma unroll
  for (int ct = 0; ct < 64; ++ct) {
    MM(ct)                       // consume slot ct&7 (tile ct)
    if (ct + PD < 64) PF(ct + PD)  // THEN refill the freed slot with tile ct+8
  }
#undef PF
#undef MM

  __syncthreads();  // bsh/rdsh visible (first barrier in the kernel)
  const float rv0 = rdsh[l15], rv1 = rdsh[16 + l15];
  f32x4 accY[2][2];

  if (MODE == 0) {
    // T -> Xs raw
#pragma unroll
    for (int df = 0; df < 2; ++df)
#pragma unroll
      for (int fi = 0; fi < 2; ++fi)
#pragma unroll
        for (int r = 0; r < 4; ++r)
          Xs[fi * 16 + l15][d0 + df * 16 + quad * 4 + r] = acc[df][fi][r];
    __syncthreads();
    f32x4 acc2[2][2] = {};
    epiGemm(Xs, WA, d0, quad, l15, acc2);
    __syncthreads();
#pragma unroll
    for (int df = 0; df < 2; ++df)
#pragma unroll
      for (int fi = 0; fi < 2; ++fi)
#pragma unroll
        for (int r = 0; r < 4; ++r) {
          int d = d0 + df * 16 + quad * 4 + r;
          float rv = fi ? rv1 : rv0;
          Xs[fi * 16 + l15][d] = fmaxf((acc2[df][fi][r] + bsh[d]) * rv, 0.f);
        }
    __syncthreads();
    f32x4 acc3[2][2] = {};
    epiGemm(Xs, WB, d0, quad, l15, acc3);
#pragma unroll
    for (int df = 0; df < 2; ++df)
#pragma unroll
      for (int fi = 0; fi < 2; ++fi) accY[df][fi] = acc3[df][fi];
  } else {
#pragma unroll
    for (int df = 0; df < 2; ++df)
#pragma unroll
      for (int fi = 0; fi < 2; ++fi)
#pragma unroll
        for (int r = 0; r < 4; ++r) {
          int d = d0 + df * 16 + quad * 4 + r;
          float rv = fi ? rv1 : rv0;
          Xs[fi * 16 + l15][d] = fmaxf((acc[df][fi][r] + bsh[d]) * rv, 0.f);
        }
    __syncthreads();
    if (MODE == 2) {
      float* outB = out + (size_t)(batch * NN + i0) * DD;
#pragma unroll
      for (int u = 0; u < 4; ++u) {
        int c = tid + 256 * u;
        int i = c >> 5, f4 = (c & 31) * 4;
        *(float4*)(outB + (size_t)i * DD + f4) = *(const float4*)&Xs[i][f4];
      }
      return;
    }
    f32x4 acc2[2][2] = {};
    epiGemm(Xs, WA, d0, quad, l15, acc2);
#pragma unroll
    for (int df = 0; df < 2; ++df)
#pragma unroll
      for (int fi = 0; fi < 2; ++fi) accY[df][fi] = acc2[df][fi];
  }

  // frag-tiled store of accY via LDS bounce
  __syncthreads();
  _Float16* Yst = (_Float16*)Xs;
#pragma unroll
  for (int df = 0; df < 2; ++df)
#pragma unroll
    for (int fi = 0; fi < 2; ++fi)
#pragma unroll
      for (int r = 0; r < 4; ++r)
        Yst[(d0 + df * 16 + quad * 4 + r) * 40 + fi * 16 + l15] =
            (_Float16)accY[df][fi][r];
  __syncthreads();
  const int nt = i0 >> 5;
  _Float16* Yb = Yout + batA;
#pragma unroll
  for (int dtl = 0; dtl < 2; ++dtl) {
    const int dt = 2 * wave + dtl;
    f16x8 v = *(const f16x8*)(&Yst[(dt * 16 + l15) * 40 + quad * 8]);
    *(f16x8*)(Yb + ((size_t)(dt * 64 + nt)) * 512 + lane * 8) = v;
  }
}

// ===========================================================================
// Legacy fallback (round-0 proven) — used when workspace < 81 MB.
// Touches only Wt (96 KB) + YtA (4 MiB at +1 MiB) in workspace.
// ===========================================================================
__global__ __launch_bounds__(256) void gemmY_kernel(
    const float* __restrict__ X, const _Float16* __restrict__ Wt,
    _Float16* __restrict__ Yt) {
  const int bx = blockIdx.x;
  const int batch = bx & 7, n0 = (bx >> 3) * 32;
  const int tid = threadIdx.x, lane = tid & 63, wave = tid >> 6;
  const int quad = lane >> 4, l15 = lane & 15, d0 = wave * 32;
  const float* Xb = X + (size_t)(batch * NN + n0) * DD;
  f32x4 acc[2][2] = {};
#pragma unroll
  for (int kk = 0; kk < 128; kk += 32) {
    f16x8 a0 = *(const f16x8*)(Wt + (d0 + l15) * DD + kk + quad * 8);
    f16x8 a1 = *(const f16x8*)(Wt + (d0 + 16 + l15) * DD + kk + quad * 8);
#pragma unroll
    for (int fi = 0; fi < 2; ++fi) {
      const float* xp = Xb + (size_t)(fi * 16 + l15) * DD + kk + quad * 8;
      float4 x0 = *(const float4*)xp;
      float4 x1 = *(const float4*)(xp + 4);
      f16x8 b = {(_Float16)x0.x, (_Float16)x0.y, (_Float16)x0.z, (_Float16)x0.w,
                 (_Float16)x1.x, (_Float16)x1.y, (_Float16)x1.z, (_Float16)x1.w};
      acc[0][fi] = __builtin_amdgcn_mfma_f32_16x16x32_f16(a0, b, acc[0][fi], 0, 0, 0);
      acc[1][fi] = __builtin_amdgcn_mfma_f32_16x16x32_f16(a1, b, acc[1][fi], 0, 0, 0);
    }
  }
  _Float16* YtB = Yt + (size_t)batch * DD * NN;
#pragma unroll
  for (int df = 0; df < 2; ++df)
#pragma unroll
    for (int fi = 0; fi < 2; ++fi)
#pragma unroll
      for (int r = 0; r < 4; ++r)
        YtB[(size_t)(d0 + df * 16 + quad * 4 + r) * NN + n0 + fi * 16 + l15] =
            (_Float16)acc[df][fi][r];
}

template<bool LAST>
__global__ __launch_bounds__(256) void agg_kernel(
    const float* __restrict__ adj, const _Float16* __restrict__ Yt,
    const float* __restrict__ bias, const _Float16* __restrict__ Wn,
    _Float16* __restrict__ Ytn, float* __restrict__ out) {
  __shared__ _Float16 Bsl[2][32 * 64];
  __shared__ float Xs[32][132];
  __shared__ float bsh[128];
  __shared__ float rd[32];

  const int tid = threadIdx.x, bx = blockIdx.x;
  const int batch = bx & 7, i0 = (bx >> 3) * 32;
  const int lane = tid & 63, wave = tid >> 6;
  const int quad = lane >> 4, l15 = lane & 15, d0 = wave * 32;
  const int ai = tid >> 3, ac = tid & 7;
  const int sc = ac ^ (ai & 7);

  const float* adjR = adj + (size_t)(batch * NN + i0 + ai) * NN + ac * 8;
  const _Float16* YtB = Yt + (size_t)batch * DD * NN;
  const _Float16* Ya0 = YtB + (size_t)(d0 + l15) * NN;
  const _Float16* Ya1 = YtB + (size_t)(d0 + 16 + l15) * NN;

  if (tid < 128) bsh[tid] = bias[tid];

  f32x4 acc[2][2] = {};
  float rowsum = 0.f;

  float4 av0 = *(const float4*)(adjR);
  float4 av1 = *(const float4*)(adjR + 4);
  f16x8 a[2][2];
#pragma unroll
  for (int k2 = 0; k2 < 2; ++k2) {
    a[k2][0] = *(const f16x8*)(Ya0 + k2 * 32 + quad * 8);
    a[k2][1] = *(const f16x8*)(Ya1 + k2 * 32 + quad * 8);
  }

  for (int ko = 0; ko < 32; ++ko) {
    rowsum += ((av0.x + av0.y) + (av0.z + av0.w)) + ((av1.x + av1.y) + (av1.z + av1.w));
    f16x8 h = {(_Float16)av0.x, (_Float16)av0.y, (_Float16)av0.z, (_Float16)av0.w,
               (_Float16)av1.x, (_Float16)av1.y, (_Float16)av1.z, (_Float16)av1.w};
    *(f16x8*)(&Bsl[ko & 1][ai * 64 + sc * 8]) = h;
    f16x8 an[2][2];
    if (ko < 31) {
      const int kb = (ko + 1) * 64;
      av0 = *(const float4*)(adjR + kb);
      av1 = *(const float4*)(adjR + kb + 4);
#pragma unroll
      for (int k2 = 0; k2 < 2; ++k2) {
        an[k2][0] = *(const f16x8*)(Ya0 + kb + k2 * 32 + quad * 8);
        an[k2][1] = *(const f16x8*)(Ya1 + kb + k2 * 32 + quad * 8);
      }
    }
    __syncthreads();
    const _Float16* B = Bsl[ko & 1];
#pragma unroll
    for (int k2 = 0; k2 < 2; ++k2)
#pragma unroll
      for (int fi = 0; fi < 2; ++fi) {
        const int row = fi * 16 + l15;
        const int ch = (k2 * 4 + quad) ^ (row & 7);
        f16x8 b = *(const f16x8*)(&B[row * 64 + ch * 8]);
        acc[0][fi] = __builtin_amdgcn_mfma_f32_16x16x32_f16(a[k2][0], b, acc[0][fi], 0, 0, 0);
        acc[1][fi] = __builtin_amdgcn_mfma_f32_16x16x32_f16(a[k2][1], b, acc[1][fi], 0, 0, 0);
      }
#pragma unroll
    for (int k2 = 0; k2 < 2; ++k2) { a[k2][0] = an[k2][0]; a[k2][1] = an[k2][1]; }
  }

  rowsum += __shfl_xor(rowsum, 1);
  rowsum += __shfl_xor(rowsum, 2);
  rowsum += __shfl_xor(rowsum, 4);
  if (ac == 0) rd[ai] = 1.0f / (rowsum + 1.0f);
  __syncthreads();

#pragma unroll
  for (int df = 0; df < 2; ++df)
#pragma unroll
    for (int fi = 0; fi < 2; ++fi)
#pragma unroll
      for (int r = 0; r < 4; ++r) {
        int d = d0 + df * 16 + quad * 4 + r;
        int i = fi * 16 + l15;
        Xs[i][d] = fmaxf((acc[df][fi][r] + bsh[d]) * rd[i], 0.f);
      }
  __syncthreads();

  if (LAST) {
    float* outB = out + (size_t)(batch * NN + i0) * DD;
#pragma unroll
    for (int u = 0; u < 4; ++u) {
      int c = tid + 256 * u;
      int i = c >> 5, f4 = (c & 31) * 4;
      *(float4*)(outB + (size_t)i * DD + f4) = *(const float4*)&Xs[i][f4];
    }
  } else {
    f32x4 acc2[2][2] = {};
    epiGemm(Xs, Wn, d0, quad, l15, acc2);
    _Float16* YnB = Ytn + (size_t)batch * DD * NN;
#pragma unroll
    for (int df = 0; df < 2; ++df)
#pragma unroll
      for (int fi = 0; fi < 2; ++fi)
#pragma unroll
        for (int r = 0; r < 4; ++r)
          YnB[(size_t)(d0 + df * 16 + quad * 4 + r) * NN + i0 + fi * 16 + l15] =
              (_Float16)acc2[df][fi][r];
  }
}

extern "C" void kernel_launch(void* const* d_in, const int* in_sizes, int n_in,
                              void* d_out, int out_size, void* d_ws, size_t ws_size,
                              hipStream_t stream) {
  const float* x0   = (const float*)d_in[0];   // [8,2048,128]
  const float* adj  = (const float*)d_in[1];   // [8,2048,2048]
  const float* W    = (const float*)d_in[2];   // [3,128,128]
  const float* bias = (const float*)d_in[3];   // [3,128]
  float* out = (float*)d_out;

  _Float16* Wt   = (_Float16*)d_ws;                             // 96 KB
  float*    rdg  = (float*)((char*)d_ws + (1u << 17));          // 64 KB
  _Float16* Xt   = (_Float16*)((char*)d_ws + (1u << 20));       // 4 MiB
  _Float16* Y1t  = (_Float16*)((char*)d_ws + (5u << 20));       // 4 MiB
  _Float16* Y2t  = (_Float16*)((char*)d_ws + (9u << 20));       // 4 MiB
  _Float16* adjH = (_Float16*)((char*)d_ws + (16u << 20));      // 64 MiB ends at 80 MiB

  const bool big = ws_size >= (81ull << 20);

  dim3 blk(256);
  prep_kernel<<<192, blk, 0, stream>>>(W, Wt);
  if (big) {
    prepAll_kernel<<<1536, blk, 0, stream>>>(adj, adjH, rdg, x0, Xt);
    // layer 1 (W0 folded into epilogue, + fused layer-2 Linear)
    aggP_kernel<0><<<512, blk, 0, stream>>>(adjH, rdg, Xt, bias, Wt, Wt + 16384, Y1t, nullptr);
    // layer 2 (+ fused layer-3 Linear)
    aggP_kernel<1><<<512, blk, 0, stream>>>(adjH, rdg, Y1t, bias + 128, Wt + 32768, nullptr, Y2t, nullptr);
    // layer 3 -> fp32 out
    aggP_kernel<2><<<512, blk, 0, stream>>>(adjH, rdg, Y2t, bias + 256, nullptr, nullptr, nullptr, out);
  } else {
    // self-contained legacy path: only Wt + YtA in workspace, d_out as scratch
    _Float16* YtA  = Xt;
    _Float16* YtB_ = (_Float16*)d_out;
    gemmY_kernel<<<512, blk, 0, stream>>>(x0, Wt, YtA);
    agg_kernel<false><<<512, blk, 0, stream>>>(adj, YtA,  bias,       Wt + 16384, YtB_, nullptr);
    agg_kernel<false><<<512, blk, 0, stream>>>(adj, YtB_, bias + 128, Wt + 32768, YtA,  nullptr);
    agg_kernel<true ><<<512, blk, 0, stream>>>(adj, YtA,  bias + 256, nullptr,    nullptr, out);
  }
}